// Round 6
// baseline (217.811 us; speedup 1.0000x reference)
//
#include <hip/hip_runtime.h>

// Problem constants (from reference)
#define N_COLS 500000
#define M1 257            // rows in relation
#define B_VECS 8
#define ABS_MAX_F 1023.0f
#define REL_ELEMS ((size_t)M1 * (size_t)N_COLS)   // 128,500,000
#define ROW_SPLIT 4       // grid.y splits the row loop for TLP

typedef float f32x4 __attribute__((ext_vector_type(4)));
typedef int   i32x4 __attribute__((ext_vector_type(4)));

// Initialize the 8 "recognized" output slots to 1.0 (true).
// Main kernel overwrites with 0.0 on the (rare) failure path.
__global__ void am_init_recognized(float* __restrict__ rec) {
    int t = threadIdx.x;
    if (t < B_VECS) rec[t] = 1.0f;
}

// One thread handles 4 adjacent columns x ~64 rows (row chunk = blockIdx.y).
// Hot loop is fully branch-free: float4 read -> saturating count-add ->
// float4 write, with a 2-op/col running-min tracking the (never-occurring)
// "final value <= 0" condition. Exact `recognized` resolution happens in a
// cold post-loop path that recomputes from global memory.
// R6: NT hints removed (A/B isolate — they were never tested alone).
__global__ __launch_bounds__(256, 8) void am_main_kernel(
    const float* __restrict__ rel_in,
    const int*   __restrict__ vec_in,
    float*       __restrict__ rel_out,
    float*       __restrict__ rec_out)
{
    int t  = blockIdx.x * blockDim.x + threadIdx.x;
    int j0 = t * 4;
    if (j0 >= N_COLS) return;

    const int chunk = blockIdx.y;
    const int r0 = (chunk * M1) / ROW_SPLIT;        // 0,64,128,192
    const int r1 = ((chunk + 1) * M1) / ROW_SPLIT;  // 64,128,192,257

    // Load and validate the 8 indices for each of the 4 columns.
    // _validate: (v < 0 || v > 256) -> 256   (int inputs: no NaN possible)
    int idx[B_VECS][4];
    #pragma unroll
    for (int b = 0; b < B_VECS; ++b) {
        i32x4 v = *reinterpret_cast<const i32x4*>(vec_in + (size_t)b * N_COLS + j0);
        #pragma unroll
        for (int c = 0; c < 4; ++c)
            idx[b][c] = ((unsigned)v[c] > 256u) ? 256 : v[c];
    }

    // Per-column running min of post-update values at incremented cells.
    // Stays 1.0 unless some incremented cell ends <= 0 (never on real data).
    float bmin[4] = {1.0f, 1.0f, 1.0f, 1.0f};

    const float* in_p  = rel_in  + j0;
    float*       out_p = rel_out + j0;

    #pragma unroll 4
    for (int i = r0; i < r1; ++i) {
        f32x4 v = *reinterpret_cast<const f32x4*>(in_p + (size_t)i * N_COLS);
        #pragma unroll
        for (int c = 0; c < 4; ++c) {
            int cnt = 0;
            #pragma unroll
            for (int b = 0; b < B_VECS; ++b) cnt += (idx[b][c] == i) ? 1 : 0;
            // Sequential saturating +1 x cnt == min(orig + cnt, 1023)
            // (valid since inputs are in [0, 1023]). For cnt==0 this is
            // bit-exact identity: v is an integer-valued float <= 1023.
            float nv = fminf(v[c] + (float)cnt, ABS_MAX_F);
            bmin[c] = fminf(bmin[c], (cnt > 0) ? nv : 1.0f);  // branch-free flag
            v[c] = nv;
        }
        *reinterpret_cast<f32x4*>(out_p + (size_t)i * N_COLS) = v;
    }

    // Cold exact path: never taken on valid data (orig >= 0, cnt >= 1 -> nv >= 1).
    if (__builtin_expect(bmin[0] <= 0.0f || bmin[1] <= 0.0f ||
                         bmin[2] <= 0.0f || bmin[3] <= 0.0f, 0)) {
        #pragma unroll
        for (int c = 0; c < 4; ++c) {
            if (bmin[c] > 0.0f) continue;
            for (int b = 0; b < B_VECS; ++b) {
                int row = idx[b][c];
                if (row < r0 || row >= r1) continue;
                float orig = rel_in[(size_t)row * N_COLS + j0 + c];
                int cnt = 0;
                for (int bb = 0; bb < B_VECS; ++bb) cnt += (idx[bb][c] == row) ? 1 : 0;
                float nv = fminf(orig + (float)cnt, ABS_MAX_F);
                if (nv <= 0.0f) rec_out[b] = 0.0f;  // all writers write 0.0: race-safe
            }
        }
    }
}

extern "C" void kernel_launch(void* const* d_in, const int* in_sizes, int n_in,
                              void* d_out, int out_size, void* d_ws, size_t ws_size,
                              hipStream_t stream) {
    const float* rel = (const float*)d_in[0];   // (257, 500000) float32
    const int*   vec = (const int*)d_in[1];     // (8, 500000) int32
    float* out     = (float*)d_out;             // relation (128.5M) ++ recognized (8)
    float* rec_out = out + REL_ELEMS;

    am_init_recognized<<<1, 64, 0, stream>>>(rec_out);

    int threads = N_COLS / 4;                        // 125,000
    dim3 grid((threads + 255) / 256, ROW_SPLIT);     // 489 x 4 blocks
    am_main_kernel<<<grid, 256, 0, stream>>>(rel, vec, out, rec_out);
}

// Round 7
// 195.993 us; speedup vs baseline: 1.1113x; 1.1113x over previous
//
#include <hip/hip_runtime.h>

// Problem constants (from reference)
#define N_COLS 500000
#define M1 257            // rows in relation
#define B_VECS 8
#define ABS_MAX_F 1023.0f
#define REL_ELEMS ((size_t)M1 * (size_t)N_COLS)   // 128,500,000
#define ROW_SPLIT 2       // grid.y splits the row loop (3912 waves, all co-resident)
#define G 8               // rows per load/store burst group

typedef float f32x4 __attribute__((ext_vector_type(4)));
typedef int   i32x4 __attribute__((ext_vector_type(4)));

// Initialize the 8 "recognized" output slots to 1.0 (true).
// Main kernel overwrites with 0.0 on the (rare) failure path.
__global__ void am_init_recognized(float* __restrict__ rec) {
    int t = threadIdx.x;
    if (t < B_VECS) rec[t] = 1.0f;
}

// One thread: 4 adjacent columns x ~128 rows. Rows processed in groups of 8:
// 8 NT loads issued back-to-back (8KB/wave read burst, 8 loads in flight),
// branch-free compute, then 8 NT stores back-to-back. NT keeps the 1GB
// relation stream from thrashing L2/L3 (round-6 A/B: NT is worth ~11us).
__global__ __launch_bounds__(256) void am_main_kernel(
    const float* __restrict__ rel_in,
    const int*   __restrict__ vec_in,
    float*       __restrict__ rel_out,
    float*       __restrict__ rec_out)
{
    int t  = blockIdx.x * blockDim.x + threadIdx.x;
    int j0 = t * 4;
    if (j0 >= N_COLS) return;

    const int chunk = blockIdx.y;
    const int r0 = (chunk * M1) / ROW_SPLIT;        // 0,128
    const int r1 = ((chunk + 1) * M1) / ROW_SPLIT;  // 128,257

    // Load and validate the 8 indices for each of the 4 columns.
    // _validate: (v < 0 || v > 256) -> 256   (int inputs: no NaN possible)
    int idx[B_VECS][4];
    #pragma unroll
    for (int b = 0; b < B_VECS; ++b) {
        i32x4 v = *reinterpret_cast<const i32x4*>(vec_in + (size_t)b * N_COLS + j0);
        #pragma unroll
        for (int c = 0; c < 4; ++c)
            idx[b][c] = ((unsigned)v[c] > 256u) ? 256 : v[c];
    }

    // Per-column running min of post-update values at incremented cells.
    // Stays 1.0 unless some incremented cell ends <= 0 (never on real data).
    float bmin[4] = {1.0f, 1.0f, 1.0f, 1.0f};

    const float* in_p  = rel_in  + j0;
    float*       out_p = rel_out + j0;

    int i = r0;
    // Main body: groups of G rows, load-burst / compute / store-burst.
    for (; i + G <= r1; i += G) {
        f32x4 v[G];
        #pragma unroll
        for (int g = 0; g < G; ++g)
            v[g] = __builtin_nontemporal_load(
                reinterpret_cast<const f32x4*>(in_p + (size_t)(i + g) * N_COLS));
        #pragma unroll
        for (int g = 0; g < G; ++g) {
            const int row = i + g;
            #pragma unroll
            for (int c = 0; c < 4; ++c) {
                int cnt = 0;
                #pragma unroll
                for (int b = 0; b < B_VECS; ++b) cnt += (idx[b][c] == row) ? 1 : 0;
                // Sequential saturating +1 x cnt == min(orig + cnt, 1023)
                // (valid: inputs in [0,1023]; bit-exact identity for cnt==0)
                float nv = fminf(v[g][c] + (float)cnt, ABS_MAX_F);
                bmin[c] = fminf(bmin[c], (cnt > 0) ? nv : 1.0f);  // branch-free flag
                v[g][c] = nv;
            }
        }
        #pragma unroll
        for (int g = 0; g < G; ++g)
            __builtin_nontemporal_store(v[g],
                reinterpret_cast<f32x4*>(out_p + (size_t)(i + g) * N_COLS));
    }
    // Remainder rows (chunk 1 has 129 rows).
    for (; i < r1; ++i) {
        f32x4 v = __builtin_nontemporal_load(
            reinterpret_cast<const f32x4*>(in_p + (size_t)i * N_COLS));
        #pragma unroll
        for (int c = 0; c < 4; ++c) {
            int cnt = 0;
            #pragma unroll
            for (int b = 0; b < B_VECS; ++b) cnt += (idx[b][c] == i) ? 1 : 0;
            float nv = fminf(v[c] + (float)cnt, ABS_MAX_F);
            bmin[c] = fminf(bmin[c], (cnt > 0) ? nv : 1.0f);
            v[c] = nv;
        }
        __builtin_nontemporal_store(v,
            reinterpret_cast<f32x4*>(out_p + (size_t)i * N_COLS));
    }

    // Cold exact path: never taken on valid data (orig >= 0, cnt >= 1 -> nv >= 1).
    if (__builtin_expect(bmin[0] <= 0.0f || bmin[1] <= 0.0f ||
                         bmin[2] <= 0.0f || bmin[3] <= 0.0f, 0)) {
        #pragma unroll
        for (int c = 0; c < 4; ++c) {
            if (bmin[c] > 0.0f) continue;
            for (int b = 0; b < B_VECS; ++b) {
                int row = idx[b][c];
                if (row < r0 || row >= r1) continue;
                float orig = rel_in[(size_t)row * N_COLS + j0 + c];
                int cnt = 0;
                for (int bb = 0; bb < B_VECS; ++bb) cnt += (idx[bb][c] == row) ? 1 : 0;
                float nv = fminf(orig + (float)cnt, ABS_MAX_F);
                if (nv <= 0.0f) rec_out[b] = 0.0f;  // all writers write 0.0: race-safe
            }
        }
    }
}

extern "C" void kernel_launch(void* const* d_in, const int* in_sizes, int n_in,
                              void* d_out, int out_size, void* d_ws, size_t ws_size,
                              hipStream_t stream) {
    const float* rel = (const float*)d_in[0];   // (257, 500000) float32
    const int*   vec = (const int*)d_in[1];     // (8, 500000) int32
    float* out     = (float*)d_out;             // relation (128.5M) ++ recognized (8)
    float* rec_out = out + REL_ELEMS;

    am_init_recognized<<<1, 64, 0, stream>>>(rec_out);

    int threads = N_COLS / 4;                        // 125,000
    dim3 grid((threads + 255) / 256, ROW_SPLIT);     // 489 x 2 blocks
    am_main_kernel<<<grid, 256, 0, stream>>>(rel, vec, out, rec_out);
}